// Round 1
// baseline (326.056 us; speedup 1.0000x reference)
//
#include <hip/hip_runtime.h>
#include <hip/hip_cooperative_groups.h>

namespace cg = cooperative_groups;

#define C 128
#define H 256
#define W 256
#define HW (H * W)
#define CHW (C * H * W)
#define NTAB 16

// PyTorch bicubic kernel, a = -0.75
__device__ __forceinline__ float cubic075(float u) {
    float au = fabsf(u);
    float near_ = (1.25f * au - 2.25f) * au * au + 1.0f;
    float far_  = -0.75f * (((au - 5.0f) * au + 8.0f) * au - 4.0f);
    return au <= 1.0f ? near_ : (au < 2.0f ? far_ : 0.0f);
}

// Weights for output index o of _bicubic_weight_matrix(768, 4)[128:384]
__device__ __forceinline__ void bicubic_w4(int o, float* w4) {
    const float scale = 4.0f / 768.0f;
    float src = ((float)(o + 128) + 0.5f) * scale - 0.5f;
    float i0f = floorf(src);
    float t = src - i0f;
    int i0 = (int)i0f;
    w4[0] = w4[1] = w4[2] = w4[3] = 0.0f;
#pragma unroll
    for (int j = 0; j < 4; ++j) {
        int off = j - 1;
        float wv = cubic075(t - (float)off);
        int idx = i0 + off;
        idx = idx < 0 ? 0 : (idx > 3 ? 3 : idx);
        w4[idx] += wv;
    }
}

__device__ __forceinline__ void channel_stats(const float* __restrict__ ws, int c,
                                              float& mean, float& stdv) {
    float s = 0.0f, s2 = 0.0f;
#pragma unroll
    for (int k = 0; k < 8; ++k) { s += ws[c * 8 + k]; s2 += ws[1024 + c * 8 + k]; }
    const float n = (float)HW;
    mean = s / n;
    float var = (s2 - s * s / n) / (n - 1.0f);
    stdv = sqrtf(var);
}

// ---------------- Fused cooperative kernel ----------------
// 1024 blocks x 256 threads, all co-resident (4 blocks/CU).
// Phase 1 : block b = (c=b>>3, seg=b&7) loads its 32 KB of pre_x into
//           registers, reduces sum/sumsq partials into ws[b], ws[1024+b].
// grid.sync()
// Phase 2a: normalize the register-held pre chunk with global channel stats
//           (pre_x touched from HBM exactly once).
// Phase 2b: real-half bicubic map, work unit b (row o = b&255, group g = b>>8).
__global__ __launch_bounds__(256, 4) void fused_kernel(
    const float* __restrict__ x,
    const float* __restrict__ mean_table, const float* __restrict__ std_table,
    const float* __restrict__ weight, const float* __restrict__ bias,
    const int* __restrict__ yA, const int* __restrict__ xA,
    const int* __restrict__ pyA, const int* __restrict__ pxA,
    float* __restrict__ ws, float* __restrict__ out) {
    int b = blockIdx.x;
    int t = threadIdx.x;

    // ---- Phase 1: stats partials; keep data in registers ----
    const float4* pre4 = (const float4*)(x + CHW);
    size_t base1 = (size_t)b * 2048 + t;
    float4 v[8];
    float s = 0.0f, s2 = 0.0f;
#pragma unroll
    for (int k = 0; k < 8; ++k) {
        float4 vv = pre4[base1 + k * 256];
        v[k] = vv;
        s  += vv.x + vv.y + vv.z + vv.w;
        s2 += vv.x * vv.x + vv.y * vv.y + vv.z * vv.z + vv.w * vv.w;
    }
#pragma unroll
    for (int off = 32; off > 0; off >>= 1) {
        s  += __shfl_down(s, off);
        s2 += __shfl_down(s2, off);
    }
    __shared__ float sd[8];
    int wid = t >> 6;
    if ((t & 63) == 0) { sd[wid] = s; sd[4 + wid] = s2; }
    __syncthreads();
    if (t == 0) {
        ws[b]        = sd[0] + sd[1] + sd[2] + sd[3];
        ws[1024 + b] = sd[4] + sd[5] + sd[6] + sd[7];
    }
    __threadfence();           // release ws writes device-wide (cross-XCD)
    cg::this_grid().sync();
    __threadfence();           // acquire side before reading ws

    // ---- Phase 2a: normalize register-held pre chunk ----
    {
        int c = b >> 3;        // whole chunk lies in one channel
        float mean, stdv;
        channel_stats(ws, c, mean, stdv);
        float sp = weight[c] / stdv;
        float bp = bias[c] - mean * sp;
        float4* outp = (float4*)(out + CHW);
#pragma unroll
        for (int k = 0; k < 8; ++k) {
            float4 r;
            r.x = v[k].x * sp + bp;
            r.y = v[k].y * sp + bp;
            r.z = v[k].z * sp + bp;
            r.w = v[k].w * sp + bp;
            outp[base1 + k * 256] = r;
        }
    }

    // ---- Phase 2b: real-half bicubic map ----
    {
        int o = b & 255;
        int g = b >> 8;
        __shared__ float patchM[16 * 32];
        __shared__ float patchI[16 * 32];
        __shared__ float Am[4 * 32], Ai[4 * 32], Wgt[32], Bs[32];
        {
            int cc = t & 31;
            int e0 = t >> 5;  // 0..7
            int c = g * 32 + cc;
            float mean, stdv;
            channel_stats(ws, c, mean, stdv);
            int ya = min(max(*yA, 0), 15);
            int xa = min(max(*xA, 0), 15);
            int py = *pyA, px = *pxA;
#pragma unroll
            for (int e = e0; e < 16; e += 8) {
                int row = min(max(ya + (e >> 2) - 1, 0), NTAB - 1);
                int col = min(max(xa + (e & 3) - 1, 0), NTAB - 1);
                float m, sv;
                if (row == py && col == px) { m = mean; sv = stdv; }
                else {
                    m  = mean_table[(row * NTAB + col) * C + c];
                    sv = std_table[(row * NTAB + col) * C + c];
                }
                patchM[e * 32 + cc] = m;
                patchI[e * 32 + cc] = 1.0f / sv;
            }
            if (e0 == 0) { Wgt[cc] = weight[c]; Bs[cc] = bias[c]; }
        }
        __syncthreads();
        float wy[4];
        bicubic_w4(o, wy);
        {
            int xx = (t >> 5) & 3;
            int cc = t & 31;
            const float* src = (t < 128) ? patchM : patchI;
            float a = 0.0f;
#pragma unroll
            for (int y = 0; y < 4; ++y) a += wy[y] * src[(y * 4 + xx) * 32 + cc];
            if (t < 128) Am[xx * 32 + cc] = a;
            else         Ai[xx * 32 + cc] = a;
        }
        __syncthreads();

        int w = t >> 6, l = t & 63;
        float wx[4][4];
#pragma unroll
        for (int e = 0; e < 4; ++e) bicubic_w4(4 * l + e, wx[e]);
        const float4* xin = (const float4*)x;
        float4* outp = (float4*)out;
#pragma unroll
        for (int k = 0; k < 8; ++k) {
            int cc = w * 8 + k;                    // channel uniform per wave
            int c = g * 32 + cc;
            size_t base = ((size_t)c * HW + o * W) / 4 + l;
            float4 v4 = xin[base];
            float wgt = Wgt[cc], bsv = Bs[cc];
            float am[4], ai[4];
#pragma unroll
            for (int q = 0; q < 4; ++q) { am[q] = Am[q * 32 + cc]; ai[q] = Ai[q * 32 + cc]; }
            float r[4], vv[4] = {v4.x, v4.y, v4.z, v4.w};
#pragma unroll
            for (int e = 0; e < 4; ++e) {
                float m = 0.0f, iv = 0.0f;
#pragma unroll
                for (int q = 0; q < 4; ++q) {
                    m  += wx[e][q] * am[q];
                    iv += wx[e][q] * ai[q];
                }
                r[e] = (vv[e] - m) * iv * wgt + bsv;
            }
            float4 ro = {r[0], r[1], r[2], r[3]};
            outp[base] = ro;
        }
    }
}

// ---------------- Fallback path (previous verified two-kernel version) ----------------
__global__ __launch_bounds__(256) void stats_kernel(const float* __restrict__ x,
                                                    float* __restrict__ ws) {
    int c = blockIdx.x >> 3;
    int seg = blockIdx.x & 7;
    const float4* x4 = (const float4*)(x + CHW) + (size_t)c * (HW / 4) + seg * 2048;
    float s = 0.0f, s2 = 0.0f;
#pragma unroll
    for (int k = 0; k < 8; ++k) {
        float4 v = x4[k * 256 + threadIdx.x];
        s  += v.x + v.y + v.z + v.w;
        s2 += v.x * v.x + v.y * v.y + v.z * v.z + v.w * v.w;
    }
#pragma unroll
    for (int off = 32; off > 0; off >>= 1) {
        s  += __shfl_down(s, off);
        s2 += __shfl_down(s2, off);
    }
    __shared__ float sd[8];
    int wid = threadIdx.x >> 6;
    if ((threadIdx.x & 63) == 0) { sd[wid] = s; sd[4 + wid] = s2; }
    __syncthreads();
    if (threadIdx.x == 0) {
        ws[c * 8 + seg]        = sd[0] + sd[1] + sd[2] + sd[3];
        ws[1024 + c * 8 + seg] = sd[4] + sd[5] + sd[6] + sd[7];
    }
}

__global__ __launch_bounds__(256) void main_kernel(
    const float* __restrict__ x,
    const float* __restrict__ mean_table, const float* __restrict__ std_table,
    const float* __restrict__ weight, const float* __restrict__ bias,
    const int* __restrict__ yA, const int* __restrict__ xA,
    const int* __restrict__ pyA, const int* __restrict__ pxA,
    const float* __restrict__ ws, float* __restrict__ out) {
    int b = blockIdx.x;
    int t = threadIdx.x;
    if (b < 1024) {
        int o = b & 255;
        int g = b >> 8;
        __shared__ float patchM[16 * 32];
        __shared__ float patchI[16 * 32];
        __shared__ float Am[4 * 32], Ai[4 * 32], Wgt[32], Bs[32];
        {
            int cc = t & 31;
            int e0 = t >> 5;
            int c = g * 32 + cc;
            float mean, stdv;
            channel_stats(ws, c, mean, stdv);
            int ya = min(max(*yA, 0), 15);
            int xa = min(max(*xA, 0), 15);
            int py = *pyA, px = *pxA;
#pragma unroll
            for (int e = e0; e < 16; e += 8) {
                int row = min(max(ya + (e >> 2) - 1, 0), NTAB - 1);
                int col = min(max(xa + (e & 3) - 1, 0), NTAB - 1);
                float m, sv;
                if (row == py && col == px) { m = mean; sv = stdv; }
                else {
                    m  = mean_table[(row * NTAB + col) * C + c];
                    sv = std_table[(row * NTAB + col) * C + c];
                }
                patchM[e * 32 + cc] = m;
                patchI[e * 32 + cc] = 1.0f / sv;
            }
            if (e0 == 0) { Wgt[cc] = weight[c]; Bs[cc] = bias[c]; }
        }
        __syncthreads();
        float wy[4];
        bicubic_w4(o, wy);
        {
            int xx = (t >> 5) & 3;
            int cc = t & 31;
            const float* src = (t < 128) ? patchM : patchI;
            float a = 0.0f;
#pragma unroll
            for (int y = 0; y < 4; ++y) a += wy[y] * src[(y * 4 + xx) * 32 + cc];
            if (t < 128) Am[xx * 32 + cc] = a;
            else         Ai[xx * 32 + cc] = a;
        }
        __syncthreads();

        int w = t >> 6, l = t & 63;
        float wx[4][4];
#pragma unroll
        for (int e = 0; e < 4; ++e) bicubic_w4(4 * l + e, wx[e]);
        const float4* xin = (const float4*)x;
        float4* outp = (float4*)out;
#pragma unroll
        for (int k = 0; k < 8; ++k) {
            int cc = w * 8 + k;
            int c = g * 32 + cc;
            size_t base = ((size_t)c * HW + o * W) / 4 + l;
            float4 v4 = xin[base];
            float wgt = Wgt[cc], bsv = Bs[cc];
            float r[4], vv[4] = {v4.x, v4.y, v4.z, v4.w};
#pragma unroll
            for (int e = 0; e < 4; ++e) {
                float m = 0.0f, iv = 0.0f;
#pragma unroll
                for (int q = 0; q < 4; ++q) {
                    m  += wx[e][q] * Am[q * 32 + cc];
                    iv += wx[e][q] * Ai[q * 32 + cc];
                }
                r[e] = (vv[e] - m) * iv * wgt + bsv;
            }
            float4 ro = {r[0], r[1], r[2], r[3]};
            outp[base] = ro;
        }
    } else {
        int bb = b - 1024;
        __shared__ float Sp[C], Bp[C];
        if (t < C) {
            float mean, stdv;
            channel_stats(ws, t, mean, stdv);
            float sp = weight[t] / stdv;
            Sp[t] = sp;
            Bp[t] = bias[t] - mean * sp;
        }
        __syncthreads();
        const float4* xin = (const float4*)(x + CHW);
        float4* outp = (float4*)(out + CHW);
        int i = bb * 256 + t;
#pragma unroll
        for (int k = 0; k < 8; ++k) {
            int j = i + k * 262144;
            float4 v4 = xin[j];
            int c = j >> 14;
            float sp = Sp[c], bp = Bp[c];
            float4 r;
            r.x = v4.x * sp + bp;
            r.y = v4.y * sp + bp;
            r.z = v4.z * sp + bp;
            r.w = v4.w * sp + bp;
            outp[j] = r;
        }
    }
}

extern "C" void kernel_launch(void* const* d_in, const int* in_sizes, int n_in,
                              void* d_out, int out_size, void* d_ws, size_t ws_size,
                              hipStream_t stream) {
    const float* x          = (const float*)d_in[0];
    const float* mean_table = (const float*)d_in[1];
    const float* std_table  = (const float*)d_in[2];
    const float* weight     = (const float*)d_in[3];
    const float* bias       = (const float*)d_in[4];
    const int* yA  = (const int*)d_in[5];
    const int* xA  = (const int*)d_in[6];
    const int* pyA = (const int*)d_in[7];
    const int* pxA = (const int*)d_in[8];
    float* out = (float*)d_out;
    float* ws  = (float*)d_ws;

    void* args[] = {(void*)&x, (void*)&mean_table, (void*)&std_table, (void*)&weight,
                    (void*)&bias, (void*)&yA, (void*)&xA, (void*)&pyA, (void*)&pxA,
                    (void*)&ws, (void*)&out};
    hipError_t err = hipLaunchCooperativeKernel((void*)fused_kernel, dim3(1024),
                                                dim3(256), args, 0, stream);
    if (err != hipSuccess) {
        // Fallback: previous verified two-kernel path.
        stats_kernel<<<C * 8, 256, 0, stream>>>(x, ws);
        main_kernel<<<2048, 256, 0, stream>>>(x, mean_table, std_table, weight, bias,
                                              yA, xA, pyA, pxA, ws, out);
    }
}

// Round 3
// 133.879 us; speedup vs baseline: 2.4355x; 2.4355x over previous
//
#include <hip/hip_runtime.h>

#define C 128
#define H 256
#define W 256
#define HW (H * W)
#define CHW (C * H * W)
#define NTAB 16

typedef float nt4 __attribute__((ext_vector_type(4)));

__device__ __forceinline__ void nt_store4(const float4& v, float4* p) {
    nt4 tmp = {v.x, v.y, v.z, v.w};
    __builtin_nontemporal_store(tmp, (nt4*)p);
}

// PyTorch bicubic kernel, a = -0.75
__device__ __forceinline__ float cubic075(float u) {
    float au = fabsf(u);
    float near_ = (1.25f * au - 2.25f) * au * au + 1.0f;
    float far_  = -0.75f * (((au - 5.0f) * au + 8.0f) * au - 4.0f);
    return au <= 1.0f ? near_ : (au < 2.0f ? far_ : 0.0f);
}

// Weights for output index o of _bicubic_weight_matrix(768, 4)[128:384]
__device__ __forceinline__ void bicubic_w4(int o, float* w4) {
    const float scale = 4.0f / 768.0f;
    float src = ((float)(o + 128) + 0.5f) * scale - 0.5f;
    float i0f = floorf(src);
    float t = src - i0f;
    int i0 = (int)i0f;
    w4[0] = w4[1] = w4[2] = w4[3] = 0.0f;
#pragma unroll
    for (int j = 0; j < 4; ++j) {
        int off = j - 1;
        float wv = cubic075(t - (float)off);
        int idx = i0 + off;
        idx = idx < 0 ? 0 : (idx > 3 ? 3 : idx);
        w4[idx] += wv;
    }
}

// ---------------- Stage 1: per-channel partial sums over pre_x ----------------
// grid = C*8 blocks of 256 threads; block (c,seg) reduces 8192 elements and
// writes its partial to ws[c*8+seg] (sum) / ws[1024 + c*8+seg] (sumsq).
// Deterministic slots -> no atomics -> no memset dispatch needed.
__global__ __launch_bounds__(256) void stats_kernel(const float* __restrict__ x,
                                                    float* __restrict__ ws) {
    int c = blockIdx.x >> 3;
    int seg = blockIdx.x & 7;
    const float4* x4 = (const float4*)(x + CHW) + (size_t)c * (HW / 4) + seg * 2048;
    float s = 0.0f, s2 = 0.0f;
#pragma unroll
    for (int k = 0; k < 8; ++k) {
        float4 v = x4[k * 256 + threadIdx.x];
        s  += v.x + v.y + v.z + v.w;
        s2 += v.x * v.x + v.y * v.y + v.z * v.z + v.w * v.w;
    }
#pragma unroll
    for (int off = 32; off > 0; off >>= 1) {
        s  += __shfl_down(s, off);
        s2 += __shfl_down(s2, off);
    }
    __shared__ float sd[8];
    int wid = threadIdx.x >> 6;
    if ((threadIdx.x & 63) == 0) { sd[wid] = s; sd[4 + wid] = s2; }
    __syncthreads();
    if (threadIdx.x == 0) {
        ws[c * 8 + seg]        = sd[0] + sd[1] + sd[2] + sd[3];
        ws[1024 + c * 8 + seg] = sd[4] + sd[5] + sd[6] + sd[7];
    }
}

__device__ __forceinline__ void channel_stats(const float* __restrict__ ws, int c,
                                              float& mean, float& stdv) {
    float s = 0.0f, s2 = 0.0f;
#pragma unroll
    for (int k = 0; k < 8; ++k) { s += ws[c * 8 + k]; s2 += ws[1024 + c * 8 + k]; }
    const float n = (float)HW;
    mean = s / n;
    float var = (s2 - s * s / n) / (n - 1.0f);
    stdv = sqrtf(var);
}

// ---------------- Stage 2: fused finalize + map ----------------
// blocks [0,1024): real half. block = (row o, channel-group g of 32).
//   Block preamble rebuilds the 4x4 patch for its 32 channels from the
//   (L2-resident) tables + partial sums, y-contracts into LDS Am/Ai[4][32],
//   then each wave streams one full row per channel with float4 (1KB/wave).
// blocks [1024,2048): pre half. Block preamble builds per-channel affine in
//   LDS, then elementwise float4 map.
// Output stores are non-temporal: out is write-once, keep x L3-resident.
__global__ __launch_bounds__(256) void main_kernel(
    const float* __restrict__ x,
    const float* __restrict__ mean_table, const float* __restrict__ std_table,
    const float* __restrict__ weight, const float* __restrict__ bias,
    const int* __restrict__ yA, const int* __restrict__ xA,
    const int* __restrict__ pyA, const int* __restrict__ pxA,
    const float* __restrict__ ws, float* __restrict__ out) {
    int b = blockIdx.x;
    int t = threadIdx.x;
    if (b < 1024) {
        int o = b & 255;
        int g = b >> 8;
        __shared__ float patchM[16 * 32];
        __shared__ float patchI[16 * 32];
        __shared__ float Am[4 * 32], Ai[4 * 32], Wgt[32], Bs[32];
        {
            int cc = t & 31;
            int e0 = t >> 5;  // 0..7
            int c = g * 32 + cc;
            float mean, stdv;
            channel_stats(ws, c, mean, stdv);
            int ya = min(max(*yA, 0), 15);
            int xa = min(max(*xA, 0), 15);
            int py = *pyA, px = *pxA;
#pragma unroll
            for (int e = e0; e < 16; e += 8) {
                int row = min(max(ya + (e >> 2) - 1, 0), NTAB - 1);
                int col = min(max(xa + (e & 3) - 1, 0), NTAB - 1);
                float m, s;
                if (row == py && col == px) { m = mean; s = stdv; }
                else {
                    m = mean_table[(row * NTAB + col) * C + c];
                    s = std_table[(row * NTAB + col) * C + c];
                }
                patchM[e * 32 + cc] = m;
                patchI[e * 32 + cc] = 1.0f / s;
            }
            if (e0 == 0) { Wgt[cc] = weight[c]; Bs[cc] = bias[c]; }
        }
        __syncthreads();
        float wy[4];
        bicubic_w4(o, wy);
        {
            int xx = (t >> 5) & 3;
            int cc = t & 31;
            const float* src = (t < 128) ? patchM : patchI;
            float a = 0.0f;
#pragma unroll
            for (int y = 0; y < 4; ++y) a += wy[y] * src[(y * 4 + xx) * 32 + cc];
            if (t < 128) Am[xx * 32 + cc] = a;
            else         Ai[xx * 32 + cc] = a;
        }
        __syncthreads();

        int w = t >> 6, l = t & 63;
        float wx[4][4];
#pragma unroll
        for (int e = 0; e < 4; ++e) bicubic_w4(4 * l + e, wx[e]);
        const float4* xin = (const float4*)x;
        float4* outp = (float4*)out;
#pragma unroll
        for (int k = 0; k < 8; ++k) {
            int cc = w * 8 + k;                    // channel uniform per wave
            int c = g * 32 + cc;
            size_t base = ((size_t)c * HW + o * W) / 4 + l;
            float4 v = xin[base];
            float wgt = Wgt[cc], bsv = Bs[cc];
            float am[4], ai[4];
#pragma unroll
            for (int q = 0; q < 4; ++q) { am[q] = Am[q * 32 + cc]; ai[q] = Ai[q * 32 + cc]; }
            float r[4], vv[4] = {v.x, v.y, v.z, v.w};
#pragma unroll
            for (int e = 0; e < 4; ++e) {
                float m = 0.0f, iv = 0.0f;
#pragma unroll
                for (int q = 0; q < 4; ++q) {
                    m  += wx[e][q] * am[q];
                    iv += wx[e][q] * ai[q];
                }
                r[e] = (vv[e] - m) * iv * wgt + bsv;
            }
            float4 ro = {r[0], r[1], r[2], r[3]};
            nt_store4(ro, &outp[base]);
        }
    } else {
        int bb = b - 1024;
        __shared__ float Sp[C], Bp[C];
        if (t < C) {
            float mean, stdv;
            channel_stats(ws, t, mean, stdv);
            float sp = weight[t] / stdv;
            Sp[t] = sp;
            Bp[t] = bias[t] - mean * sp;
        }
        __syncthreads();
        const float4* xin = (const float4*)(x + CHW);
        float4* outp = (float4*)(out + CHW);
        int i = bb * 256 + t;
#pragma unroll
        for (int k = 0; k < 8; ++k) {
            int j = i + k * 262144;          // CHW/4 = 2,097,152 float4 total
            float4 v = xin[j];
            int c = j >> 14;                 // HW/4 = 16384 float4 per channel
            float sp = Sp[c], bp = Bp[c];    // uniform per wave -> broadcast
            float4 r;
            r.x = v.x * sp + bp;
            r.y = v.y * sp + bp;
            r.z = v.z * sp + bp;
            r.w = v.w * sp + bp;
            nt_store4(r, &outp[j]);
        }
    }
}

extern "C" void kernel_launch(void* const* d_in, const int* in_sizes, int n_in,
                              void* d_out, int out_size, void* d_ws, size_t ws_size,
                              hipStream_t stream) {
    const float* x          = (const float*)d_in[0];
    const float* mean_table = (const float*)d_in[1];
    const float* std_table  = (const float*)d_in[2];
    const float* weight     = (const float*)d_in[3];
    const float* bias       = (const float*)d_in[4];
    const int* yA  = (const int*)d_in[5];
    const int* xA  = (const int*)d_in[6];
    const int* pyA = (const int*)d_in[7];
    const int* pxA = (const int*)d_in[8];
    float* out = (float*)d_out;
    float* ws  = (float*)d_ws;

    stats_kernel<<<C * 8, 256, 0, stream>>>(x, ws);
    main_kernel<<<2048, 256, 0, stream>>>(x, mean_table, std_table, weight, bias,
                                          yA, xA, pyA, pxA, ws, out);
}